// Round 2
// baseline (5252.511 us; speedup 1.0000x reference)
//
#include <hip/hip_runtime.h>
#include <hip/hip_bf16.h>
#include <math.h>

typedef __hip_bfloat16 bf16;

#define BATCH 64
#define NPIX 596
#define CH 34
#define PC 256
#define TILE 16
#define NTILE 38   // ceil(596/16)

static __device__ __forceinline__ float b2f(const bf16 v){ return __bfloat162float(v); }
static __device__ __forceinline__ bf16  f2b(const float v){ return __float2bfloat16(v); }
static __device__ __forceinline__ float eluf(float x){ return x > 0.f ? x : expm1f(x); }

// ---------------------------------------------------------------------------
// K1: conv1+relu -> conv2+relu -> feats (B, 596, 34) f32.  One block per batch.
// ---------------------------------------------------------------------------
__global__ __launch_bounds__(256) void k_conv_feats(
    const float* __restrict__ x,
    const float* __restrict__ w1, const float* __restrict__ b1,
    const float* __restrict__ w2, const float* __restrict__ b2,
    float* __restrict__ feats)
{
  __shared__ float sw1[16*4*2*2];   // 256
  __shared__ float sb1[16];
  __shared__ float sw2[32*16*2*2];  // 2048
  __shared__ float sb2[32];
  __shared__ float h1[16*150*5];    // 12000 floats = 48KB
  const int b = blockIdx.x, t = threadIdx.x;
  const float* xb = x + (size_t)b * 4*151*6;

  sw1[t]=w1[t];
  if (t<16) sb1[t]=b1[t];
  for (int i=t;i<2048;i+=256) sw2[i]=w2[i];
  if (t<32) sb2[t]=b2[t];
  __syncthreads();

  // conv1: out (16,150,5), x (4,151,6)
  for (int i=t;i<12000;i+=256){
    int oc = i/750, rem = i-oc*750;
    int r = rem/5, cc = rem-(rem/5)*5;
    float acc = sb1[oc];
    #pragma unroll
    for (int ic=0;ic<4;ic++){
      const float* xp = xb + ic*906 + r*6 + cc;
      const float* wp = sw1 + oc*16 + ic*4;
      acc += xp[0]*wp[0] + xp[1]*wp[1] + xp[6]*wp[2] + xp[7]*wp[3];
    }
    h1[i] = fmaxf(acc, 0.f);
  }
  __syncthreads();

  // conv2: out (32,149,4) -> feats[p][oc], p = r*4+c
  float* fb = feats + (size_t)b*NPIX*CH;
  for (int i=t;i<32*NPIX;i+=256){
    int oc = i/NPIX, p = i - oc*NPIX;
    int r = p>>2, cc = p&3;
    float acc = sb2[oc];
    #pragma unroll
    for (int ic=0;ic<16;ic++){
      const float* hp = h1 + ic*750 + r*5 + cc;
      const float* wp = sw2 + oc*64 + ic*4;
      acc += hp[0]*wp[0] + hp[1]*wp[1] + hp[5]*wp[2] + hp[6]*wp[3];
    }
    fb[p*CH+oc] = fmaxf(acc, 0.f);
  }
  for (int p=t;p<NPIX;p+=256){
    fb[p*CH+32] = (float)(p&3)*0.25f;          // xc = col/4
    fb[p*CH+33] = (float)(p>>2)*(1.0f/149.0f); // yc = row/149
  }
}

// ---------------------------------------------------------------------------
// K2: proj (feats @ w + b), LayerNorm over whole (4,596,64) per batch,
// affine g/beta, write bf16 (B,4,596,64). One block per batch; two-pass
// recompute (proj is only 34 MACs/elem).
// ---------------------------------------------------------------------------
__global__ __launch_bounds__(256) void k_proj_ln(
    const float* __restrict__ feats,
    const float* __restrict__ pw, const float* __restrict__ pb,
    const float* __restrict__ g,  const float* __restrict__ beta,
    bf16* __restrict__ out)
{
  __shared__ float sw[CH*PC];   // 34*256 floats
  __shared__ float sb[PC];
  __shared__ float red[8];
  const int b = blockIdx.x, t = threadIdx.x;
  for (int i=t;i<CH*PC;i+=256) sw[i]=pw[i];
  sb[t]=pb[t];
  __syncthreads();

  const float* fb = feats + (size_t)b*NPIX*CH;
  float s=0.f, s2=0.f;
  for (int p=0;p<NPIX;p++){
    const float* fr = fb + p*CH;   // uniform across threads (scalar-cached)
    float acc = sb[t];
    #pragma unroll
    for (int e=0;e<CH;e++) acc += fr[e]*sw[e*PC+t];
    s += acc; s2 += acc*acc;
  }
  #pragma unroll
  for (int o=32;o>0;o>>=1){ s += __shfl_down(s,o); s2 += __shfl_down(s2,o); }
  if ((t&63)==0){ red[t>>6]=s; red[4+(t>>6)]=s2; }
  __syncthreads();
  const float n = (float)(NPIX*PC);
  float S  = red[0]+red[1]+red[2]+red[3];
  float S2 = red[4]+red[5]+red[6]+red[7];
  float mu = S/n;
  float var = S2/n - mu*mu;
  float rs = rsqrtf(var + 1e-5f);

  const int h = t>>6, d = t&63;
  for (int p=0;p<NPIX;p++){
    const float* fr = fb + p*CH;
    float acc = sb[t];
    #pragma unroll
    for (int e=0;e<CH;e++) acc += fr[e]*sw[e*PC+t];
    int gi = (h*NPIX+p)*64 + d;
    float y = (acc-mu)*rs*g[gi] + beta[gi];
    out[((size_t)(b*4+h)*NPIX + p)*64 + d] = f2b(y);
  }
}

// ---------------------------------------------------------------------------
// K3: fused attention.  Per block: (bh, 16-row tile).
//   A0 = elu(Q@qw + K@kw + qb + kb)   (LDS 16x596)
//   S  = A0 @ alin + alin_b           (registers, 48/thread)
//   P  = softmax(S) rows              (in-place LDS)
//   E  = P @ V  -> Ew (B,596,256) f32
// ---------------------------------------------------------------------------
__global__ __launch_bounds__(256) void k_attn(
    const bf16* __restrict__ Qb, const bf16* __restrict__ Kb, const bf16* __restrict__ Vb,
    const float* __restrict__ qw, const float* __restrict__ qbias,
    const float* __restrict__ kw, const float* __restrict__ kbias,
    const float* __restrict__ aw, const float* __restrict__ abias,
    float* __restrict__ Ew)
{
  __shared__ float sQ[TILE*64];
  __shared__ float sK[TILE*64];
  __shared__ float sA[TILE*NPIX];   // 9536 floats = 38.1KB
  const int tile = blockIdx.x;
  const int bh = blockIdx.y;
  const int b = bh>>2, h = bh&3;
  const int t = threadIdx.x;
  const int i0 = tile*TILE;
  const bf16* Qp = Qb + (size_t)bh*NPIX*64;
  const bf16* Kp = Kb + (size_t)bh*NPIX*64;

  for (int i=t;i<TILE*64;i+=256){
    int r = i>>6, row = i0 + r;
    bool v = row < NPIX;
    sQ[i] = v ? b2f(Qp[(size_t)row*64 + (i&63)]) : 0.f;
    sK[i] = v ? b2f(Kp[(size_t)row*64 + (i&63)]) : 0.f;
  }
  __syncthreads();

  // A0 phase: each thread owns columns j = t, t+256, t+512
  for (int s=0;s<3;s++){
    int j = t + s*256;
    if (j >= NPIX) break;
    float acc[TILE];
    #pragma unroll
    for (int i=0;i<TILE;i++) acc[i]=0.f;
    for (int d=0; d<64; d++){
      float qv = qw[d*NPIX + j];
      float kv = kw[d*NPIX + j];
      #pragma unroll
      for (int i=0;i<TILE;i++)
        acc[i] += sQ[i*64+d]*qv + sK[i*64+d]*kv;
    }
    float bias = qbias[j] + kbias[j];
    #pragma unroll
    for (int i=0;i<TILE;i++)
      sA[i*NPIX + j] = eluf(acc[i] + bias);
  }
  __syncthreads();

  // S phase: stream alin rows, accumulate in registers
  const int j0=t, j1=t+256, j2=t+512;
  const bool v2 = (j2 < NPIX);
  float s0[TILE], s1[TILE], s2[TILE];
  #pragma unroll
  for (int i=0;i<TILE;i++){ s0[i]=0.f; s1[i]=0.f; s2[i]=0.f; }
  for (int c=0;c<NPIX;c++){
    const float* ar = aw + (size_t)c*NPIX;
    float a0v = ar[j0];
    float a1v = ar[j1];
    float a2v = v2 ? ar[j2] : 0.f;
    #pragma unroll
    for (int i=0;i<TILE;i++){
      float av = sA[i*NPIX+c];
      s0[i] += av*a0v; s1[i] += av*a1v; s2[i] += av*a2v;
    }
  }
  __syncthreads();   // everyone done reading A0
  {
    float b0 = abias[j0], b1v = abias[j1];
    float b2v = v2 ? abias[j2] : 0.f;
    #pragma unroll
    for (int i=0;i<TILE;i++){
      sA[i*NPIX+j0] = s0[i] + b0;
      sA[i*NPIX+j1] = s1[i] + b1v;
      if (v2) sA[i*NPIX+j2] = s2[i] + b2v;
    }
  }
  __syncthreads();

  // softmax: 16 groups of 16 lanes, one row each
  {
    int row = t>>4, lane = t&15;
    float* Sr = sA + row*NPIX;
    float mx = -1e30f;
    for (int j=lane;j<NPIX;j+=16) mx = fmaxf(mx, Sr[j]);
    #pragma unroll
    for (int o=8;o>0;o>>=1) mx = fmaxf(mx, __shfl_xor(mx, o, 16));
    float sum = 0.f;
    for (int j=lane;j<NPIX;j+=16){ float e = __expf(Sr[j]-mx); Sr[j]=e; sum+=e; }
    #pragma unroll
    for (int o=8;o>0;o>>=1) sum += __shfl_xor(sum, o, 16);
    float inv = 1.f/sum;
    for (int j=lane;j<NPIX;j+=16) Sr[j] *= inv;
  }
  __syncthreads();

  // P @ V
  const bf16* Vp = Vb + (size_t)bh*NPIX*64;
  const int d = t&63, ig = t>>6;
  for (int pass=0; pass<4; pass++){
    int i = pass*4 + ig;
    const float* Pr = sA + i*NPIX;
    float acc = 0.f;
    for (int j=0;j<NPIX;j++)
      acc += Pr[j] * b2f(Vp[(size_t)j*64 + d]);
    int p = i0 + i;
    if (p < NPIX)
      Ew[((size_t)b*NPIX + p)*256 + h*64 + d] = acc;
  }
}

// ---------------------------------------------------------------------------
// K4: lin1 + relu + per-batch LN partial stats (atomic).
// ---------------------------------------------------------------------------
__global__ __launch_bounds__(64) void k_lin1(
    const float* __restrict__ Ew, const float* __restrict__ w, const float* __restrict__ bias,
    float* __restrict__ F, float* __restrict__ stats)
{
  __shared__ float se[256];
  const int row = blockIdx.x;   // b*596 + p
  const int t = threadIdx.x;    // 64
  const float* er = Ew + (size_t)row*256;
  for (int i=t;i<256;i+=64) se[i]=er[i];
  __syncthreads();
  float acc = bias[t];
  for (int e=0;e<256;e++) acc += se[e]*w[e*64+t];
  acc = fmaxf(acc, 0.f);
  F[(size_t)row*64+t] = acc;
  float s = acc, s2 = acc*acc;
  #pragma unroll
  for (int o=32;o>0;o>>=1){ s += __shfl_down(s,o); s2 += __shfl_down(s2,o); }
  if (t==0){
    int b = row/NPIX;
    atomicAdd(&stats[b*2],   s);
    atomicAdd(&stats[b*2+1], s2);
  }
}

// ---------------------------------------------------------------------------
// K5: LN (no affine) + max over pixels (commutes: rs>0) + lin2 + elu -> out.
// ---------------------------------------------------------------------------
__global__ __launch_bounds__(256) void k_final(
    const float* __restrict__ F, const float* __restrict__ stats,
    const float* __restrict__ w2, const float* __restrict__ b2v,
    float* __restrict__ out)
{
  __shared__ float cm[256];
  __shared__ float nm[64];
  const int b = blockIdx.x, t = threadIdx.x;
  const int d = t&63, grp = t>>6;
  const float* Fb = F + (size_t)b*NPIX*64;
  float m = -1e30f;
  for (int p=grp;p<NPIX;p+=4) m = fmaxf(m, Fb[p*64+d]);
  cm[t]=m;
  __syncthreads();
  if (t<64){
    float mm = fmaxf(fmaxf(cm[t],cm[t+64]), fmaxf(cm[t+128],cm[t+192]));
    const float n = (float)(NPIX*64);
    float S = stats[b*2], S2 = stats[b*2+1];
    float mu = S/n, var = S2/n - mu*mu;
    nm[t] = (mm - mu) * rsqrtf(var + 1e-5f);
  }
  __syncthreads();
  if (t<10){
    float acc = b2v[t];
    for (int e=0;e<64;e++) acc += nm[e]*w2[e*10+t];
    out[b*10+t] = eluf(acc);
  }
}

// ---------------------------------------------------------------------------
extern "C" void kernel_launch(void* const* d_in, const int* in_sizes, int n_in,
                              void* d_out, int out_size, void* d_ws, size_t ws_size,
                              hipStream_t stream)
{
  const float* x       = (const float*)d_in[0];
  const float* conv1_w = (const float*)d_in[1];
  const float* conv1_b = (const float*)d_in[2];
  const float* conv2_w = (const float*)d_in[3];
  const float* conv2_b = (const float*)d_in[4];
  const float* kp_w    = (const float*)d_in[5];
  const float* kp_b    = (const float*)d_in[6];
  const float* qp_w    = (const float*)d_in[7];
  const float* qp_b    = (const float*)d_in[8];
  const float* vp_w    = (const float*)d_in[9];
  const float* vp_b    = (const float*)d_in[10];
  const float* klin_w  = (const float*)d_in[11];
  const float* klin_b  = (const float*)d_in[12];
  const float* qlin_w  = (const float*)d_in[13];
  const float* qlin_b  = (const float*)d_in[14];
  const float* alin_w  = (const float*)d_in[15];
  const float* alin_b  = (const float*)d_in[16];
  const float* knorm_g = (const float*)d_in[17];
  const float* knorm_b = (const float*)d_in[18];
  const float* qnorm_g = (const float*)d_in[19];
  const float* qnorm_b = (const float*)d_in[20];
  const float* vnorm_g = (const float*)d_in[21];
  const float* vnorm_b = (const float*)d_in[22];
  const float* lin1_w  = (const float*)d_in[23];
  const float* lin1_b  = (const float*)d_in[24];
  const float* lin2_w  = (const float*)d_in[25];
  const float* lin2_b  = (const float*)d_in[26];

  // workspace layout (floats)
  float* feats = (float*)d_ws;                       // 64*596*34   = 1,296,896 f
  float* Ew    = feats + (size_t)BATCH*NPIX*CH;      // 64*596*256  = 9,764,864 f
  float* F     = Ew    + (size_t)BATCH*NPIX*256;     // 64*596*64   = 2,441,216 f
  float* stats = F     + (size_t)BATCH*NPIX*64;      // 128 f
  bf16*  Qb    = (bf16*)(stats + 128);               // 9,764,864 bf16 each
  bf16*  Kb    = Qb + (size_t)BATCH*4*NPIX*64;
  bf16*  Vb    = Kb + (size_t)BATCH*4*NPIX*64;

  hipMemsetAsync(stats, 0, 128*sizeof(float), stream);

  k_conv_feats<<<BATCH, 256, 0, stream>>>(x, conv1_w, conv1_b, conv2_w, conv2_b, feats);

  k_proj_ln<<<BATCH, 256, 0, stream>>>(feats, kp_w, kp_b, knorm_g, knorm_b, Kb);
  k_proj_ln<<<BATCH, 256, 0, stream>>>(feats, qp_w, qp_b, qnorm_g, qnorm_b, Qb);
  k_proj_ln<<<BATCH, 256, 0, stream>>>(feats, vp_w, vp_b, vnorm_g, vnorm_b, Vb);

  dim3 g3(NTILE, BATCH*4);
  k_attn<<<g3, 256, 0, stream>>>(Qb, Kb, Vb, qlin_w, qlin_b, klin_w, klin_b,
                                 alin_w, alin_b, Ew);

  k_lin1<<<BATCH*NPIX, 64, 0, stream>>>(Ew, lin1_w, lin1_b, F, stats);

  k_final<<<BATCH, 256, 0, stream>>>(F, stats, lin2_w, lin2_b, (float*)d_out);
}

// Round 3
// 1914.000 us; speedup vs baseline: 2.7443x; 2.7443x over previous
//
#include <hip/hip_runtime.h>
#include <hip/hip_bf16.h>
#include <math.h>

typedef __hip_bfloat16 bf16;
typedef unsigned short ushort;
typedef __attribute__((ext_vector_type(8))) short short8;
typedef __attribute__((ext_vector_type(4))) float float4v;

#define BATCH 64
#define NPIX 596
#define NP 608          // padded to 38*16
#define CH 34
#define PC 256

static __device__ __forceinline__ float b2f(const bf16 v){ return __bfloat162float(v); }
static __device__ __forceinline__ bf16  f2b(const float v){ return __float2bfloat16(v); }
static __device__ __forceinline__ ushort f2bu(float v){ bf16 h = __float2bfloat16(v); return *(ushort*)&h; }
static __device__ __forceinline__ float eluf(float x){ return x > 0.f ? x : expm1f(x); }

// chunk LDS layout: element (n, k) k in [0,32); granule q=k>>3 swizzled.
// halfword offset of granule start:
static __device__ __forceinline__ int chidx(int n, int q){
  return n*32 + ((q ^ ((n>>1)&3))<<3);
}

// ---------------------------------------------------------------------------
// K1: conv1+relu -> conv2+relu -> feats (B, 596, 34) f32.  One block per batch.
// ---------------------------------------------------------------------------
__global__ __launch_bounds__(256) void k_conv_feats(
    const float* __restrict__ x,
    const float* __restrict__ w1, const float* __restrict__ b1,
    const float* __restrict__ w2, const float* __restrict__ b2,
    float* __restrict__ feats)
{
  __shared__ float sw1[256];
  __shared__ float sb1[16];
  __shared__ float sw2[2048];
  __shared__ float sb2[32];
  __shared__ float h1[16*150*5];
  const int b = blockIdx.x, t = threadIdx.x;
  const float* xb = x + (size_t)b * 4*151*6;

  sw1[t]=w1[t];
  if (t<16) sb1[t]=b1[t];
  for (int i=t;i<2048;i+=256) sw2[i]=w2[i];
  if (t<32) sb2[t]=b2[t];
  __syncthreads();

  for (int i=t;i<12000;i+=256){
    int oc = i/750, rem = i-oc*750;
    int r = rem/5, cc = rem-(rem/5)*5;
    float acc = sb1[oc];
    #pragma unroll
    for (int ic=0;ic<4;ic++){
      const float* xp = xb + ic*906 + r*6 + cc;
      const float* wp = sw1 + oc*16 + ic*4;
      acc += xp[0]*wp[0] + xp[1]*wp[1] + xp[6]*wp[2] + xp[7]*wp[3];
    }
    h1[i] = fmaxf(acc, 0.f);
  }
  __syncthreads();

  float* fb = feats + (size_t)b*NPIX*CH;
  for (int i=t;i<32*NPIX;i+=256){
    int oc = i/NPIX, p = i - oc*NPIX;
    int r = p>>2, cc = p&3;
    float acc = sb2[oc];
    #pragma unroll
    for (int ic=0;ic<16;ic++){
      const float* hp = h1 + ic*750 + r*5 + cc;
      const float* wp = sw2 + oc*64 + ic*4;
      acc += hp[0]*wp[0] + hp[1]*wp[1] + hp[5]*wp[2] + hp[6]*wp[3];
    }
    fb[p*CH+oc] = fmaxf(acc, 0.f);
  }
  for (int p=t;p<NPIX;p+=256){
    fb[p*CH+32] = (float)(p&3)*0.25f;
    fb[p*CH+33] = (float)(p>>2)*(1.0f/149.0f);
  }
}

// ---------------------------------------------------------------------------
// K_prep: build bf16 transposed weights.
//   alinT[n][c] = alin_w[c][n]   (608x608, zero-padded)
//   WqkT [n][k] = k<64 ? qlin_w[k][n] : klin_w[k-64][n]   (608x128)
// ---------------------------------------------------------------------------
__global__ __launch_bounds__(128) void k_prep(
    const float* __restrict__ aw, const float* __restrict__ qw, const float* __restrict__ kw,
    ushort* __restrict__ alinT, ushort* __restrict__ WqkT)
{
  const int n = blockIdx.x, t = threadIdx.x;
  for (int c=t;c<NP;c+=128)
    alinT[n*NP + c] = (n<NPIX && c<NPIX) ? f2bu(aw[(size_t)c*NPIX + n]) : 0;
  for (int k=t;k<128;k+=128)
    WqkT[n*128 + k] = (n<NPIX) ? f2bu(k<64 ? qw[(size_t)k*NPIX + n] : kw[(size_t)(k-64)*NPIX + n]) : 0;
}

// ---------------------------------------------------------------------------
// P1: proj stats.  grid (4 ptiles, 64 b, 3 which).  atomic partial sums.
// ---------------------------------------------------------------------------
__global__ __launch_bounds__(256) void k_proj_p1(
    const float* __restrict__ feats,
    const float* __restrict__ kpw, const float* __restrict__ kpb,
    const float* __restrict__ qpw, const float* __restrict__ qpb,
    const float* __restrict__ vpw, const float* __restrict__ vpb,
    float* __restrict__ statsP)
{
  __shared__ float sw[CH*PC];
  __shared__ float sb[PC];
  __shared__ float sf[149*CH];
  __shared__ float red[8];
  const int pt = blockIdx.x, b = blockIdx.y, which = blockIdx.z, t = threadIdx.x;
  const float* W  = which==0 ? kpw : which==1 ? qpw : vpw;
  const float* Bv = which==0 ? kpb : which==1 ? qpb : vpb;
  for (int i=t;i<CH*PC;i+=256) sw[i]=W[i];
  sb[t]=Bv[t];
  const float* fb = feats + ((size_t)b*NPIX + pt*149)*CH;
  for (int i=t;i<149*CH;i+=256) sf[i]=fb[i];
  __syncthreads();
  float s=0.f, s2=0.f;
  for (int p=0;p<149;p++){
    float acc = sb[t];
    const float* fr = sf + p*CH;
    #pragma unroll
    for (int e=0;e<CH;e++) acc += fr[e]*sw[e*PC+t];
    s += acc; s2 += acc*acc;
  }
  #pragma unroll
  for (int o=32;o>0;o>>=1){ s += __shfl_down(s,o); s2 += __shfl_down(s2,o); }
  if ((t&63)==0){ red[t>>6]=s; red[4+(t>>6)]=s2; }
  __syncthreads();
  if (t==0){
    atomicAdd(&statsP[(which*64+b)*2],   red[0]+red[1]+red[2]+red[3]);
    atomicAdd(&statsP[(which*64+b)*2+1], red[4]+red[5]+red[6]+red[7]);
  }
}

// ---------------------------------------------------------------------------
// P2: proj recompute + LN + affine, write bf16 (B,4,596,64).
// ---------------------------------------------------------------------------
__global__ __launch_bounds__(256) void k_proj_p2(
    const float* __restrict__ feats,
    const float* __restrict__ kpw, const float* __restrict__ kpb,
    const float* __restrict__ qpw, const float* __restrict__ qpb,
    const float* __restrict__ vpw, const float* __restrict__ vpb,
    const float* __restrict__ kg, const float* __restrict__ kb_,
    const float* __restrict__ qg, const float* __restrict__ qb_,
    const float* __restrict__ vg, const float* __restrict__ vb_,
    const float* __restrict__ statsP,
    ushort* __restrict__ Kb, ushort* __restrict__ Qb, ushort* __restrict__ Vb)
{
  __shared__ float sw[CH*PC];
  __shared__ float sb[PC];
  __shared__ float sf[149*CH];
  const int pt = blockIdx.x, b = blockIdx.y, which = blockIdx.z, t = threadIdx.x;
  const float* W  = which==0 ? kpw : which==1 ? qpw : vpw;
  const float* Bv = which==0 ? kpb : which==1 ? qpb : vpb;
  const float* G  = which==0 ? kg  : which==1 ? qg  : vg;
  const float* Be = which==0 ? kb_ : which==1 ? qb_ : vb_;
  ushort* out     = which==0 ? Kb  : which==1 ? Qb  : Vb;
  for (int i=t;i<CH*PC;i+=256) sw[i]=W[i];
  sb[t]=Bv[t];
  const float* fb = feats + ((size_t)b*NPIX + pt*149)*CH;
  for (int i=t;i<149*CH;i+=256) sf[i]=fb[i];
  __syncthreads();
  const float n = (float)(NPIX*PC);
  const float S  = statsP[(which*64+b)*2];
  const float S2 = statsP[(which*64+b)*2+1];
  const float mu = S/n;
  const float rs = rsqrtf(S2/n - mu*mu + 1e-5f);
  const int h = t>>6, d = t&63;
  for (int p=0;p<149;p++){
    float acc = sb[t];
    const float* fr = sf + p*CH;
    #pragma unroll
    for (int e=0;e<CH;e++) acc += fr[e]*sw[e*PC+t];
    int pg = pt*149 + p;
    int gi = (h*NPIX+pg)*64 + d;
    float y = (acc-mu)*rs*G[gi] + Be[gi];
    out[((size_t)(b*4+h)*NPIX + pg)*64 + d] = f2bu(y);
  }
}

// ---------------------------------------------------------------------------
// K3: fused MFMA attention.  grid (38 row-tiles, 256 bh), 256 thr.
// LDS: strip 16x616 bf16 | chunk 608x32 bf16 swizzled | red 128 f32 = 59,136 B
// ---------------------------------------------------------------------------
__global__ __launch_bounds__(256) void k_attn(
    const ushort* __restrict__ Qb, const ushort* __restrict__ Kb, const ushort* __restrict__ Vb,
    const ushort* __restrict__ alinT, const ushort* __restrict__ WqkT,
    const float* __restrict__ qbias, const float* __restrict__ kbias,
    const float* __restrict__ abias,
    float* __restrict__ Ew)
{
  extern __shared__ __align__(16) ushort sm[];
  ushort* strip = sm;                  // 16*616 = 9856 hw
  ushort* chnk  = sm + 16*616;         // 608*32 = 19456 hw
  float*  red   = (float*)(sm + 16*616 + 608*32);  // 128 f32

  const int t = threadIdx.x;
  const int w = t>>6, l = t&63, quad = l>>4, ln = l&15;
  const int tile0 = blockIdx.x, bh = blockIdx.y;
  const int b = bh>>2, h = bh&3;
  const int row0 = tile0*16;
  const ushort* Qp = Qb + (size_t)bh*NPIX*64;
  const ushort* Kp = Kb + (size_t)bh*NPIX*64;
  const ushort* Vp = Vb + (size_t)bh*NPIX*64;

  float4v acc[10];
  #pragma unroll
  for (int i=0;i<10;i++) acc[i] = (float4v){0.f,0.f,0.f,0.f};

  // ---------------- A0 phase: A0 = elu([Q|K] @ Wqk + qb + kb) ----------------
  const int arow = row0 + ln;
  const bool arow_ok = arow < NPIX;
  for (int kk=0; kk<4; kk++){
    for (int g=t; g<2432; g+=256){
      int nn = g>>2, q = g&3;
      *(short8*)(chnk + chidx(nn,q)) = *(const short8*)(WqkT + nn*128 + kk*32 + q*8);
    }
    __syncthreads();
    short8 a = {};
    if (arow_ok){
      if (kk < 2) a = *(const short8*)(Qp + (size_t)arow*64 + kk*32 + quad*8);
      else        a = *(const short8*)(Kp + (size_t)arow*64 + (kk-2)*32 + quad*8);
    }
    #pragma unroll
    for (int i=0;i<10;i++){
      int tile = w + 4*i;
      if (tile < 38){
        short8 bf = *(const short8*)(chnk + chidx(tile*16 + ln, quad));
        acc[i] = __builtin_amdgcn_mfma_f32_16x16x32_bf16(a, bf, acc[i], 0, 0, 0);
      }
    }
    __syncthreads();
  }
  // epilogue: bias + elu -> strip bf16
  #pragma unroll
  for (int i=0;i<10;i++){
    int tile = w + 4*i;
    if (tile < 38){
      int col = tile*16 + ln;
      float qkb = (col < NPIX) ? (qbias[col] + kbias[col]) : 0.f;
      #pragma unroll
      for (int r=0;r<4;r++){
        float v = (col < NPIX) ? eluf(acc[i][r] + qkb) : 0.f;
        strip[(quad*4+r)*616 + col] = f2bu(v);
      }
    }
  }
  __syncthreads();

  // ---------------- S phase: S = A0 @ alin ----------------
  #pragma unroll
  for (int i=0;i<10;i++) acc[i] = (float4v){0.f,0.f,0.f,0.f};
  for (int kk=0; kk<19; kk++){
    for (int g=t; g<2432; g+=256){
      int nn = g>>2, q = g&3;
      *(short8*)(chnk + chidx(nn,q)) = *(const short8*)(alinT + (size_t)nn*NP + kk*32 + q*8);
    }
    __syncthreads();
    short8 a = *(const short8*)(strip + ln*616 + kk*32 + quad*8);
    #pragma unroll
    for (int i=0;i<10;i++){
      int tile = w + 4*i;
      if (tile < 38){
        short8 bf = *(const short8*)(chnk + chidx(tile*16 + ln, quad));
        acc[i] = __builtin_amdgcn_mfma_f32_16x16x32_bf16(a, bf, acc[i], 0, 0, 0);
      }
    }
    __syncthreads();
  }

  // ---------------- softmax (exact, cross-wave) ----------------
  float mx[4] = {-1e30f,-1e30f,-1e30f,-1e30f};
  #pragma unroll
  for (int i=0;i<10;i++){
    int tile = w + 4*i;
    if (tile < 38){
      int col = tile*16 + ln;
      float ab = (col < NPIX) ? abias[col] : 0.f;
      #pragma unroll
      for (int r=0;r<4;r++){
        float s = (col < NPIX) ? (acc[i][r] + ab) : -1e30f;
        acc[i][r] = s;
        mx[r] = fmaxf(mx[r], s);
      }
    }
  }
  #pragma unroll
  for (int r=0;r<4;r++){
    #pragma unroll
    for (int o=8;o>0;o>>=1) mx[r] = fmaxf(mx[r], __shfl_xor(mx[r], o, 16));
  }
  if (ln == 0){
    #pragma unroll
    for (int r=0;r<4;r++) red[w*16 + quad*4 + r] = mx[r];
  }
  __syncthreads();
  float M[4], sum[4];
  #pragma unroll
  for (int r=0;r<4;r++){
    int row = quad*4 + r;
    M[r] = fmaxf(fmaxf(red[row], red[16+row]), fmaxf(red[32+row], red[48+row]));
    sum[r] = 0.f;
  }
  #pragma unroll
  for (int i=0;i<10;i++){
    int tile = w + 4*i;
    if (tile < 38){
      #pragma unroll
      for (int r=0;r<4;r++){
        float e = (acc[i][r] > -1e29f) ? __expf(acc[i][r] - M[r]) : 0.f;
        acc[i][r] = e;
        sum[r] += e;
      }
    }
  }
  #pragma unroll
  for (int r=0;r<4;r++){
    #pragma unroll
    for (int o=8;o>0;o>>=1) sum[r] += __shfl_xor(sum[r], o, 16);
  }
  __syncthreads();   // red reuse
  if (ln == 0){
    #pragma unroll
    for (int r=0;r<4;r++) red[64 + w*16 + quad*4 + r] = sum[r];
  }
  __syncthreads();
  float inv[4];
  #pragma unroll
  for (int r=0;r<4;r++){
    int row = quad*4 + r;
    float tot = red[64+row] + red[64+16+row] + red[64+32+row] + red[64+48+row];
    inv[r] = 1.f / tot;
  }
  #pragma unroll
  for (int i=0;i<10;i++){
    int tile = w + 4*i;
    if (tile < 38){
      int col = tile*16 + ln;
      #pragma unroll
      for (int r=0;r<4;r++)
        strip[(quad*4+r)*616 + col] = f2bu(acc[i][r] * inv[r]);
    }
  }
  __syncthreads();

  // ---------------- V phase: E = P @ V ----------------
  float4v ve = (float4v){0.f,0.f,0.f,0.f};
  for (int kk=0; kk<19; kk++){
    {
      int jl = t&31, dg = t>>5;       // 32 j x 8 d-groups = 256 threads
      int jj = kk*32 + jl;
      short8 vv = {};
      if (jj < NPIX) vv = *(const short8*)(Vp + (size_t)jj*64 + dg*8);
      #pragma unroll
      for (int i2=0;i2<8;i2++){
        int d = dg*8 + i2;
        chnk[chidx(d, jl>>3) + (jl&7)] = ((ushort*)&vv)[i2];
      }
    }
    __syncthreads();
    short8 a = *(const short8*)(strip + ln*616 + kk*32 + quad*8);
    int nd = w*16 + ln;
    short8 bf = *(const short8*)(chnk + chidx(nd, quad));
    ve = __builtin_amdgcn_mfma_f32_16x16x32_bf16(a, bf, ve, 0, 0, 0);
    __syncthreads();
  }
  #pragma unroll
  for (int r=0;r<4;r++){
    int row = row0 + quad*4 + r;
    if (row < NPIX)
      Ew[((size_t)b*NPIX + row)*256 + h*64 + w*16 + ln] = ve[r];
  }
}

// ---------------------------------------------------------------------------
// K4: lin1 + relu + per-batch LN partial stats (atomic).
// ---------------------------------------------------------------------------
__global__ __launch_bounds__(64) void k_lin1(
    const float* __restrict__ Ew, const float* __restrict__ w, const float* __restrict__ bias,
    float* __restrict__ F, float* __restrict__ stats)
{
  __shared__ float se[256];
  const int row = blockIdx.x;
  const int t = threadIdx.x;
  const float* er = Ew + (size_t)row*256;
  for (int i=t;i<256;i+=64) se[i]=er[i];
  __syncthreads();
  float acc = bias[t];
  for (int e=0;e<256;e++) acc += se[e]*w[e*64+t];
  acc = fmaxf(acc, 0.f);
  F[(size_t)row*64+t] = acc;
  float s = acc, s2 = acc*acc;
  #pragma unroll
  for (int o=32;o>0;o>>=1){ s += __shfl_down(s,o); s2 += __shfl_down(s2,o); }
  if (t==0){
    int b = row/NPIX;
    atomicAdd(&stats[b*2],   s);
    atomicAdd(&stats[b*2+1], s2);
  }
}

// ---------------------------------------------------------------------------
// K5: LN (no affine) + max over pixels (commutes: rs>0) + lin2 + elu.
// ---------------------------------------------------------------------------
__global__ __launch_bounds__(256) void k_final(
    const float* __restrict__ F, const float* __restrict__ stats,
    const float* __restrict__ w2, const float* __restrict__ b2v,
    float* __restrict__ out)
{
  __shared__ float cm[256];
  __shared__ float nm[64];
  const int b = blockIdx.x, t = threadIdx.x;
  const int d = t&63, grp = t>>6;
  const float* Fb = F + (size_t)b*NPIX*64;
  float m = -1e30f;
  for (int p=grp;p<NPIX;p+=4) m = fmaxf(m, Fb[p*64+d]);
  cm[t]=m;
  __syncthreads();
  if (t<64){
    float mm = fmaxf(fmaxf(cm[t],cm[t+64]), fmaxf(cm[t+128],cm[t+192]));
    const float n = (float)(NPIX*64);
    float S = stats[b*2], S2 = stats[b*2+1];
    float mu = S/n, var = S2/n - mu*mu;
    nm[t] = (mm - mu) * rsqrtf(var + 1e-5f);
  }
  __syncthreads();
  if (t<10){
    float acc = b2v[t];
    for (int e=0;e<64;e++) acc += nm[e]*w2[e*10+t];
    out[b*10+t] = eluf(acc);
  }
}

// ---------------------------------------------------------------------------
extern "C" void kernel_launch(void* const* d_in, const int* in_sizes, int n_in,
                              void* d_out, int out_size, void* d_ws, size_t ws_size,
                              hipStream_t stream)
{
  const float* x       = (const float*)d_in[0];
  const float* conv1_w = (const float*)d_in[1];
  const float* conv1_b = (const float*)d_in[2];
  const float* conv2_w = (const float*)d_in[3];
  const float* conv2_b = (const float*)d_in[4];
  const float* kp_w    = (const float*)d_in[5];
  const float* kp_b    = (const float*)d_in[6];
  const float* qp_w    = (const float*)d_in[7];
  const float* qp_b    = (const float*)d_in[8];
  const float* vp_w    = (const float*)d_in[9];
  const float* vp_b    = (const float*)d_in[10];
  const float* klin_w  = (const float*)d_in[11];
  const float* klin_b  = (const float*)d_in[12];
  const float* qlin_w  = (const float*)d_in[13];
  const float* qlin_b  = (const float*)d_in[14];
  const float* alin_w  = (const float*)d_in[15];
  const float* alin_b  = (const float*)d_in[16];
  const float* knorm_g = (const float*)d_in[17];
  const float* knorm_b = (const float*)d_in[18];
  const float* qnorm_g = (const float*)d_in[19];
  const float* qnorm_b = (const float*)d_in[20];
  const float* vnorm_g = (const float*)d_in[21];
  const float* vnorm_b = (const float*)d_in[22];
  const float* lin1_w  = (const float*)d_in[23];
  const float* lin1_b  = (const float*)d_in[24];
  const float* lin2_w  = (const float*)d_in[25];
  const float* lin2_b  = (const float*)d_in[26];

  // workspace layout
  float* feats  = (float*)d_ws;                       // 1,296,896 f
  float* Ew     = feats + (size_t)BATCH*NPIX*CH;      // 9,764,864 f
  float* F      = Ew    + (size_t)BATCH*NPIX*256;     // 2,441,216 f
  float* statsE = F     + (size_t)BATCH*NPIX*64;      // 128 f
  float* statsP = statsE + 128;                       // 384 f
  ushort* Qb    = (ushort*)(statsP + 384);            // 9,764,864 hw each
  ushort* Kb    = Qb + (size_t)BATCH*4*NPIX*64;
  ushort* Vb    = Kb + (size_t)BATCH*4*NPIX*64;
  // alinT/WqkT overlay the F region (F is written only after attention).
  ushort* alinT = (ushort*)F;                         // 608*608 hw
  ushort* WqkT  = alinT + 400000;                     // 608*128 hw

  hipMemsetAsync(statsE, 0, 512*sizeof(float), stream);

  k_conv_feats<<<BATCH, 256, 0, stream>>>(x, conv1_w, conv1_b, conv2_w, conv2_b, feats);

  k_prep<<<NP, 128, 0, stream>>>(alin_w, qlin_w, klin_w, alinT, WqkT);

  dim3 gp(4, BATCH, 3);
  k_proj_p1<<<gp, 256, 0, stream>>>(feats, kp_w, kp_b, qp_w, qp_b, vp_w, vp_b, statsP);
  k_proj_p2<<<gp, 256, 0, stream>>>(feats, kp_w, kp_b, qp_w, qp_b, vp_w, vp_b,
                                    knorm_g, knorm_b, qnorm_g, qnorm_b, vnorm_g, vnorm_b,
                                    statsP, Kb, Qb, Vb);

  dim3 ga(38, BATCH*4);
  k_attn<<<ga, 256, 59136, stream>>>(Qb, Kb, Vb, alinT, WqkT,
                                     qlin_b, klin_b, alin_b, Ew);

  k_lin1<<<BATCH*NPIX, 64, 0, stream>>>(Ew, lin1_w, lin1_b, F, statsE);

  k_final<<<BATCH, 256, 0, stream>>>(F, statsE, lin2_w, lin2_b, (float*)d_out);
}

// Round 4
// 856.445 us; speedup vs baseline: 6.1329x; 2.2348x over previous
//
#include <hip/hip_runtime.h>
#include <hip/hip_bf16.h>
#include <math.h>

typedef __hip_bfloat16 bf16;
typedef unsigned short ushort;
typedef unsigned int u32;
typedef __attribute__((ext_vector_type(8))) short short8;
typedef __attribute__((ext_vector_type(4))) float float4v;

#define BATCH 64
#define NPIX 596
#define CH 34
#define PC 256

static __device__ __forceinline__ ushort f2bu(float v){ bf16 h = __float2bfloat16(v); return *(ushort*)&h; }
static __device__ __forceinline__ float eluf(float x){ return x > 0.f ? x : expm1f(x); }

// global -> LDS direct DMA, 16B per lane; lds dest = base + lane*16
static __device__ __forceinline__ void gload16(const ushort* g, ushort* l){
  __builtin_amdgcn_global_load_lds((const __attribute__((address_space(1))) u32*)g,
                                   (__attribute__((address_space(3))) u32*)l, 16, 0, 0);
}

// ---------------------------------------------------------------------------
// K1: conv1+relu -> conv2+relu -> feats (B, 596, 34) f32.
// ---------------------------------------------------------------------------
__global__ __launch_bounds__(256) void k_conv_feats(
    const float* __restrict__ x,
    const float* __restrict__ w1, const float* __restrict__ b1,
    const float* __restrict__ w2, const float* __restrict__ b2,
    float* __restrict__ feats)
{
  __shared__ float sw1[256];
  __shared__ float sb1[16];
  __shared__ float sw2[2048];
  __shared__ float sb2[32];
  __shared__ float h1[16*150*5];
  const int b = blockIdx.x, t = threadIdx.x;
  const float* xb = x + (size_t)b * 4*151*6;

  sw1[t]=w1[t];
  if (t<16) sb1[t]=b1[t];
  for (int i=t;i<2048;i+=256) sw2[i]=w2[i];
  if (t<32) sb2[t]=b2[t];
  __syncthreads();

  for (int i=t;i<12000;i+=256){
    int oc = i/750, rem = i-oc*750;
    int r = rem/5, cc = rem-(rem/5)*5;
    float acc = sb1[oc];
    #pragma unroll
    for (int ic=0;ic<4;ic++){
      const float* xp = xb + ic*906 + r*6 + cc;
      const float* wp = sw1 + oc*16 + ic*4;
      acc += xp[0]*wp[0] + xp[1]*wp[1] + xp[6]*wp[2] + xp[7]*wp[3];
    }
    h1[i] = fmaxf(acc, 0.f);
  }
  __syncthreads();

  float* fb = feats + (size_t)b*NPIX*CH;
  for (int i=t;i<32*NPIX;i+=256){
    int oc = i/NPIX, p = i - oc*NPIX;
    int r = p>>2, cc = p&3;
    float acc = sb2[oc];
    #pragma unroll
    for (int ic=0;ic<16;ic++){
      const float* hp = h1 + ic*750 + r*5 + cc;
      const float* wp = sw2 + oc*64 + ic*4;
      acc += hp[0]*wp[0] + hp[1]*wp[1] + hp[5]*wp[2] + hp[6]*wp[3];
    }
    fb[p*CH+oc] = fmaxf(acc, 0.f);
  }
  for (int p=t;p<NPIX;p+=256){
    fb[p*CH+32] = (float)(p&3)*0.25f;
    fb[p*CH+33] = (float)(p>>2)*(1.0f/149.0f);
  }
}

// ---------------------------------------------------------------------------
// K_prep: bf16 transposed weights.
//   alinT[640][608] : alinT[n][c] = alin[c][n], zero-padded
//   WqkT [640][128] : col k<64 -> qlin[k][n], else klin[k-64][n]
//   w1T  [64][256]  : w1T[n][e] = lin1_w[e][n]
// ---------------------------------------------------------------------------
__global__ __launch_bounds__(128) void k_prep(
    const float* __restrict__ aw, const float* __restrict__ qw, const float* __restrict__ kw,
    const float* __restrict__ l1w,
    ushort* __restrict__ alinT, ushort* __restrict__ WqkT, ushort* __restrict__ w1T)
{
  const int n = blockIdx.x, t = threadIdx.x;
  for (int c=t;c<608;c+=128)
    alinT[(size_t)n*608 + c] = (n<NPIX && c<NPIX) ? f2bu(aw[(size_t)c*NPIX + n]) : 0;
  WqkT[n*128 + t] = (n<NPIX) ? f2bu(t<64 ? qw[(size_t)t*NPIX + n] : kw[(size_t)(t-64)*NPIX + n]) : 0;
  if (n < 64)
    for (int e=t;e<256;e+=128) w1T[n*256 + e] = f2bu(l1w[(size_t)e*64 + n]);
}

// ---------------------------------------------------------------------------
// P1: proj stats. grid (4 ptiles, 64 b, 3 which). atomic partial sums.
// ---------------------------------------------------------------------------
__global__ __launch_bounds__(256) void k_proj_p1(
    const float* __restrict__ feats,
    const float* __restrict__ kpw, const float* __restrict__ kpb,
    const float* __restrict__ qpw, const float* __restrict__ qpb,
    const float* __restrict__ vpw, const float* __restrict__ vpb,
    float* __restrict__ statsP)
{
  __shared__ float sw[CH*PC];
  __shared__ float sb[PC];
  __shared__ float sf[149*CH];
  __shared__ float red[8];
  const int pt = blockIdx.x, b = blockIdx.y, which = blockIdx.z, t = threadIdx.x;
  const float* W  = which==0 ? kpw : which==1 ? qpw : vpw;
  const float* Bv = which==0 ? kpb : which==1 ? qpb : vpb;
  for (int i=t;i<CH*PC;i+=256) sw[i]=W[i];
  sb[t]=Bv[t];
  const float* fb = feats + ((size_t)b*NPIX + pt*149)*CH;
  for (int i=t;i<149*CH;i+=256) sf[i]=fb[i];
  __syncthreads();
  float s=0.f, s2=0.f;
  for (int p=0;p<149;p++){
    float acc = sb[t];
    const float* fr = sf + p*CH;
    #pragma unroll
    for (int e=0;e<CH;e++) acc += fr[e]*sw[e*PC+t];
    s += acc; s2 += acc*acc;
  }
  #pragma unroll
  for (int o=32;o>0;o>>=1){ s += __shfl_down(s,o); s2 += __shfl_down(s2,o); }
  if ((t&63)==0){ red[t>>6]=s; red[4+(t>>6)]=s2; }
  __syncthreads();
  if (t==0){
    atomicAdd(&statsP[(which*64+b)*2],   red[0]+red[1]+red[2]+red[3]);
    atomicAdd(&statsP[(which*64+b)*2+1], red[4]+red[5]+red[6]+red[7]);
  }
}

// ---------------------------------------------------------------------------
// P2: proj recompute + LN + affine -> bf16 (B,4,596,64).
// ---------------------------------------------------------------------------
__global__ __launch_bounds__(256) void k_proj_p2(
    const float* __restrict__ feats,
    const float* __restrict__ kpw, const float* __restrict__ kpb,
    const float* __restrict__ qpw, const float* __restrict__ qpb,
    const float* __restrict__ vpw, const float* __restrict__ vpb,
    const float* __restrict__ kg, const float* __restrict__ kb_,
    const float* __restrict__ qg, const float* __restrict__ qb_,
    const float* __restrict__ vg, const float* __restrict__ vb_,
    const float* __restrict__ statsP,
    ushort* __restrict__ Kb, ushort* __restrict__ Qb, ushort* __restrict__ Vb)
{
  __shared__ float sw[CH*PC];
  __shared__ float sb[PC];
  __shared__ float sf[149*CH];
  const int pt = blockIdx.x, b = blockIdx.y, which = blockIdx.z, t = threadIdx.x;
  const float* W  = which==0 ? kpw : which==1 ? qpw : vpw;
  const float* Bv = which==0 ? kpb : which==1 ? qpb : vpb;
  const float* G  = which==0 ? kg  : which==1 ? qg  : vg;
  const float* Be = which==0 ? kb_ : which==1 ? qb_ : vb_;
  ushort* out     = which==0 ? Kb  : which==1 ? Qb  : Vb;
  for (int i=t;i<CH*PC;i+=256) sw[i]=W[i];
  sb[t]=Bv[t];
  const float* fb = feats + ((size_t)b*NPIX + pt*149)*CH;
  for (int i=t;i<149*CH;i+=256) sf[i]=fb[i];
  __syncthreads();
  const float n = (float)(NPIX*PC);
  const float S  = statsP[(which*64+b)*2];
  const float S2 = statsP[(which*64+b)*2+1];
  const float mu = S/n;
  const float rs = rsqrtf(S2/n - mu*mu + 1e-5f);
  const int h = t>>6, d = t&63;
  for (int p=0;p<149;p++){
    float acc = sb[t];
    const float* fr = sf + p*CH;
    #pragma unroll
    for (int e=0;e<CH;e++) acc += fr[e]*sw[e*PC+t];
    int pg = pt*149 + p;
    int gi = (h*NPIX+pg)*64 + d;
    float y = (acc-mu)*rs*G[gi] + Be[gi];
    out[((size_t)(b*4+h)*NPIX + pg)*64 + d] = f2bu(y);
  }
}

// ---------------------------------------------------------------------------
// K3: fused MFMA attention, M=64 rows/block, N padded to 640 (40 tiles).
// grid (10 row-strips, 256 bh), 256 threads, 1 block/CU.
// LDS: strip 64x616 bf16 | 2x chunk 640x32 bf16 (swizzled) | red 256 f32
//    = 78848 + 81920 + 1024 = 161792 B
// ---------------------------------------------------------------------------
__global__ __launch_bounds__(256, 1) void k_attn(
    const ushort* __restrict__ Qb, const ushort* __restrict__ Kb, const ushort* __restrict__ Vb,
    const ushort* __restrict__ alinT, const ushort* __restrict__ WqkT,
    const float* __restrict__ qbias, const float* __restrict__ kbias,
    const float* __restrict__ abias,
    ushort* __restrict__ Ew)
{
  extern __shared__ __align__(16) ushort sm[];
  ushort* strip = sm;                    // 39424 halves
  ushort* chk0 = sm + 39424;             // 20480 halves each
  ushort* chk1 = sm + 59904;
  float*  red  = (float*)(sm + 80384);   // 256 f32

  const int t = threadIdx.x;
  const int w = t>>6, l = t&63, quad = l>>4, ln = l&15;
  const int rb = blockIdx.x, bh = blockIdx.y;
  const int b = bh>>2, h = bh&3;
  const int row0 = rb*64;
  const ushort* Qp = Qb + (size_t)bh*NPIX*64;
  const ushort* Kp = Kb + (size_t)bh*NPIX*64;
  const ushort* Vp = Vb + (size_t)bh*NPIX*64;

  // per-lane swizzled B-fragment base inside a chunk (halves); + tile*512
  const int qs = quad ^ ((ln>>1)&3);
  const int bfr = ln*32 + qs*8;

  // stage a chunk: rows n of src (row length RL), cols [kcol, kcol+32) -> buf
  auto stage = [&](const ushort* src, int RL, int kcol, ushort* buf, int iters){
    for (int j=0;j<iters;j++){
      int slot = (w*iters + j)*64 + l;
      int n = slot>>2;
      int q = (slot&3) ^ ((n>>1)&3);
      gload16(src + (size_t)n*RL + kcol + q*8, buf + (size_t)((w*iters + j)*64)*8);
    }
  };
  // V chunk: manual transpose staging (V is row-major j,d; need d-major)
  auto stageV = [&](int kk, ushort* buf){
    int jl = t&31, dg = t>>5;
    int jj = kk*32 + jl;
    short8 z = {0,0,0,0,0,0,0,0};
    short8 vv = (jj < NPIX) ? *(const short8*)(Vp + (size_t)jj*64 + dg*8) : z;
    int q = jl>>3, jo = jl&7;
    #pragma unroll
    for (int i2=0;i2<8;i2++){
      int d = dg*8 + i2;
      buf[(d*4 + (q ^ ((d>>1)&3)))*8 + jo] = ((const ushort*)&vv)[i2];
    }
  };

  float4v acc[4][10];
  #pragma unroll
  for (int ms=0;ms<4;ms++)
    #pragma unroll
    for (int i=0;i<10;i++) acc[ms][i] = (float4v){0.f,0.f,0.f,0.f};

  // ---------------- A0 = elu([Q|K] @ Wqk + qb + kb) ----------------
  short8 aq[4][4];
  #pragma unroll
  for (int kk=0;kk<4;kk++)
    #pragma unroll
    for (int ms=0;ms<4;ms++){
      int r = row0 + ms*16 + ln;
      short8 z = {0,0,0,0,0,0,0,0};
      aq[kk][ms] = (r < NPIX)
        ? *(const short8*)((kk<2 ? Qp : Kp) + (size_t)r*64 + (kk&1)*32 + quad*8) : z;
    }
  stage(WqkT, 128, 0, chk0, 10);
  __syncthreads();
  for (int kk=0;kk<4;kk++){
    if (kk<3) stage(WqkT, 128, (kk+1)*32, ((kk+1)&1) ? chk1 : chk0, 10);
    ushort* cb = (kk&1) ? chk1 : chk0;
    #pragma unroll
    for (int i=0;i<10;i++){
      short8 bf = *(const short8*)(cb + (w+4*i)*512 + bfr);
      #pragma unroll
      for (int ms=0;ms<4;ms++)
        acc[ms][i] = __builtin_amdgcn_mfma_f32_16x16x32_bf16(aq[kk][ms], bf, acc[ms][i], 0,0,0);
    }
    __syncthreads();
  }

  // stage first S chunk, then epilogue (DMA overlaps epilogue)
  stage(alinT, 608, 0, chk0, 10);
  #pragma unroll
  for (int i=0;i<10;i++){
    int t0 = w + 4*i;
    if (t0 < 38){
      int col = t0*16 + ln;
      bool cv = col < NPIX;
      float qkb = cv ? (qbias[col] + kbias[col]) : 0.f;
      #pragma unroll
      for (int ms=0;ms<4;ms++)
        #pragma unroll
        for (int r=0;r<4;r++){
          float v = 0.f;
          if (cv){ float xx = acc[ms][i][r] + qkb; v = xx > 0.f ? xx : __expf(xx) - 1.f; }
          strip[(ms*16+quad*4+r)*616 + col] = f2bu(v);
        }
    }
  }
  __syncthreads();

  // ---------------- S = A0 @ alin ----------------
  #pragma unroll
  for (int ms=0;ms<4;ms++)
    #pragma unroll
    for (int i=0;i<10;i++) acc[ms][i] = (float4v){0.f,0.f,0.f,0.f};
  for (int kk=0;kk<19;kk++){
    if (kk<18) stage(alinT, 608, (kk+1)*32, ((kk+1)&1) ? chk1 : chk0, 10);
    ushort* cb = (kk&1) ? chk1 : chk0;
    short8 af[4];
    #pragma unroll
    for (int ms=0;ms<4;ms++)
      af[ms] = *(const short8*)(strip + (ms*16+ln)*616 + kk*32 + quad*8);
    #pragma unroll
    for (int i=0;i<10;i++){
      short8 bf = *(const short8*)(cb + (w+4*i)*512 + bfr);
      #pragma unroll
      for (int ms=0;ms<4;ms++)
        acc[ms][i] = __builtin_amdgcn_mfma_f32_16x16x32_bf16(af[ms], bf, acc[ms][i], 0,0,0);
    }
    __syncthreads();
  }

  // ---------------- softmax (exact, cross-wave) ----------------
  float M_[4][4], sum[4][4], inv[4][4];
  #pragma unroll
  for (int ms=0;ms<4;ms++)
    #pragma unroll
    for (int r=0;r<4;r++) M_[ms][r] = -1e30f;
  #pragma unroll
  for (int i=0;i<10;i++){
    int col = (w+4*i)*16 + ln;
    float ab = (col < NPIX) ? abias[col] : 0.f;
    #pragma unroll
    for (int ms=0;ms<4;ms++)
      #pragma unroll
      for (int r=0;r<4;r++){
        float s = (col < NPIX) ? acc[ms][i][r] + ab : -1e30f;
        acc[ms][i][r] = s;
        M_[ms][r] = fmaxf(M_[ms][r], s);
      }
  }
  #pragma unroll
  for (int ms=0;ms<4;ms++)
    #pragma unroll
    for (int r=0;r<4;r++)
      #pragma unroll
      for (int o=8;o>0;o>>=1) M_[ms][r] = fmaxf(M_[ms][r], __shfl_xor(M_[ms][r], o, 16));
  if (ln==0){
    #pragma unroll
    for (int ms=0;ms<4;ms++)
      #pragma unroll
      for (int r=0;r<4;r++) red[(ms*16+quad*4+r)*4 + w] = M_[ms][r];
  }
  __syncthreads();
  #pragma unroll
  for (int ms=0;ms<4;ms++)
    #pragma unroll
    for (int r=0;r<4;r++){
      float4v v = *(float4v*)&red[(ms*16+quad*4+r)*4];
      M_[ms][r] = fmaxf(fmaxf(v[0],v[1]), fmaxf(v[2],v[3]));
      sum[ms][r] = 0.f;
    }
  #pragma unroll
  for (int i=0;i<10;i++)
    #pragma unroll
    for (int ms=0;ms<4;ms++)
      #pragma unroll
      for (int r=0;r<4;r++){
        float e = __expf(acc[ms][i][r] - M_[ms][r]);
        acc[ms][i][r] = e;
        sum[ms][r] += e;
      }
  #pragma unroll
  for (int ms=0;ms<4;ms++)
    #pragma unroll
    for (int r=0;r<4;r++)
      #pragma unroll
      for (int o=8;o>0;o>>=1) sum[ms][r] += __shfl_xor(sum[ms][r], o, 16);
  __syncthreads();
  if (ln==0){
    #pragma unroll
    for (int ms=0;ms<4;ms++)
      #pragma unroll
      for (int r=0;r<4;r++) red[(ms*16+quad*4+r)*4 + w] = sum[ms][r];
  }
  __syncthreads();
  #pragma unroll
  for (int ms=0;ms<4;ms++)
    #pragma unroll
    for (int r=0;r<4;r++){
      float4v v = *(float4v*)&red[(ms*16+quad*4+r)*4];
      inv[ms][r] = 1.f / (v[0]+v[1]+v[2]+v[3]);
    }
  #pragma unroll
  for (int i=0;i<10;i++){
    int t0 = w + 4*i;
    if (t0 < 38){
      int col = t0*16 + ln;
      #pragma unroll
      for (int ms=0;ms<4;ms++)
        #pragma unroll
        for (int r=0;r<4;r++)
          strip[(ms*16+quad*4+r)*616 + col] = f2bu(acc[ms][i][r] * inv[ms][r]);
    }
  }
  stageV(0, chk0);
  __syncthreads();

  // ---------------- E = P @ V ----------------
  float4v ve[4];
  #pragma unroll
  for (int ms=0;ms<4;ms++) ve[ms] = (float4v){0.f,0.f,0.f,0.f};
  for (int kk=0;kk<19;kk++){
    if (kk<18) stageV(kk+1, ((kk+1)&1) ? chk1 : chk0);
    ushort* cb = (kk&1) ? chk1 : chk0;
    short8 bf = *(const short8*)(cb + w*512 + bfr);
    #pragma unroll
    for (int ms=0;ms<4;ms++){
      short8 af = *(const short8*)(strip + (ms*16+ln)*616 + kk*32 + quad*8);
      ve[ms] = __builtin_amdgcn_mfma_f32_16x16x32_bf16(af, bf, ve[ms], 0,0,0);
    }
    __syncthreads();
  }
  #pragma unroll
  for (int ms=0;ms<4;ms++)
    #pragma unroll
    for (int r=0;r<4;r++){
      int p = row0 + ms*16 + quad*4 + r;
      if (p < NPIX)
        Ew[((size_t)b*NPIX + p)*256 + h*64 + w*16 + ln] = f2bu(ve[ms][r]);
    }
}

// ---------------------------------------------------------------------------
// K4: lin1 via MFMA + relu + per-batch LN stats. grid (10 rowblocks, 64 b).
// ---------------------------------------------------------------------------
__global__ __launch_bounds__(256) void k_lin1(
    const ushort* __restrict__ Ew, const ushort* __restrict__ w1T,
    const float* __restrict__ bias,
    float* __restrict__ F, float* __restrict__ stats)
{
  __shared__ ushort sw1[64*264];
  __shared__ float red[8];
  const int t = threadIdx.x;
  const int w = t>>6, l = t&63, quad = l>>4, ln = l&15;
  const int rb = blockIdx.x, b = blockIdx.y;
  for (int g=t; g<2048; g+=256){
    int row = g>>5, q = g&31;
    *(short8*)(sw1 + row*264 + q*8) = *(const short8*)(w1T + row*256 + q*8);
  }
  __syncthreads();
  float4v acc[4];
  #pragma unroll
  for (int ms=0;ms<4;ms++) acc[ms] = (float4v){0.f,0.f,0.f,0.f};
  #pragma unroll
  for (int kk=0;kk<8;kk++){
    short8 bf = *(const short8*)(sw1 + (w*16+ln)*264 + kk*32 + quad*8);
    #pragma unroll
    for (int ms=0;ms<4;ms++){
      int p = rb*64 + ms*16 + ln;
      size_t rowi = (size_t)b*NPIX + (p < NPIX ? p : 0);
      short8 a = *(const short8*)(Ew + rowi*256 + kk*32 + quad*8);
      acc[ms] = __builtin_amdgcn_mfma_f32_16x16x32_bf16(a, bf, acc[ms], 0,0,0);
    }
  }
  const int col = w*16 + ln;
  const float bc = bias[col];
  float s=0.f, s2=0.f;
  #pragma unroll
  for (int ms=0;ms<4;ms++)
    #pragma unroll
    for (int r=0;r<4;r++){
      int p = rb*64 + ms*16 + quad*4 + r;
      if (p < NPIX){
        float v = fmaxf(acc[ms][r] + bc, 0.f);
        F[((size_t)b*NPIX + p)*64 + col] = v;
        s += v; s2 += v*v;
      }
    }
  #pragma unroll
  for (int o=32;o>0;o>>=1){ s += __shfl_down(s,o); s2 += __shfl_down(s2,o); }
  if (l==0){ red[w]=s; red[4+w]=s2; }
  __syncthreads();
  if (t==0){
    atomicAdd(&stats[b*2],   red[0]+red[1]+red[2]+red[3]);
    atomicAdd(&stats[b*2+1], red[4]+red[5]+red[6]+red[7]);
  }
}

// ---------------------------------------------------------------------------
// K5: LN (no affine) + max over pixels (commutes: rs>0) + lin2 + elu.
// ---------------------------------------------------------------------------
__global__ __launch_bounds__(256) void k_final(
    const float* __restrict__ F, const float* __restrict__ stats,
    const float* __restrict__ w2, const float* __restrict__ b2v,
    float* __restrict__ out)
{
  __shared__ float cm[256];
  __shared__ float nm[64];
  const int b = blockIdx.x, t = threadIdx.x;
  const int d = t&63, grp = t>>6;
  const float* Fb = F + (size_t)b*NPIX*64;
  float m = -1e30f;
  for (int p=grp;p<NPIX;p+=4) m = fmaxf(m, Fb[p*64+d]);
  cm[t]=m;
  __syncthreads();
  if (t<64){
    float mm = fmaxf(fmaxf(cm[t],cm[t+64]), fmaxf(cm[t+128],cm[t+192]));
    const float n = (float)(NPIX*64);
    float S = stats[b*2], S2 = stats[b*2+1];
    float mu = S/n, var = S2/n - mu*mu;
    nm[t] = (mm - mu) * rsqrtf(var + 1e-5f);
  }
  __syncthreads();
  if (t<10){
    float acc = b2v[t];
    for (int e=0;e<64;e++) acc += nm[e]*w2[e*10+t];
    out[b*10+t] = eluf(acc);
  }
}

// ---------------------------------------------------------------------------
extern "C" void kernel_launch(void* const* d_in, const int* in_sizes, int n_in,
                              void* d_out, int out_size, void* d_ws, size_t ws_size,
                              hipStream_t stream)
{
  const float* x       = (const float*)d_in[0];
  const float* conv1_w = (const float*)d_in[1];
  const float* conv1_b = (const float*)d_in[2];
  const float* conv2_w = (const float*)d_in[3];
  const float* conv2_b = (const float*)d_in[4];
  const float* kp_w    = (const float*)d_in[5];
  const float* kp_b    = (const float*)d_in[6];
  const float* qp_w    = (const float*)d_in[7];
  const float* qp_b    = (const float*)d_in[8];
  const float* vp_w    = (const float*)d_in[9];
  const float* vp_b    = (const float*)d_in[10];
  const float* klin_w  = (const float*)d_in[11];
  const float* klin_b  = (const float*)d_in[12];
  const float* qlin_w  = (const float*)d_in[13];
  const float* qlin_b  = (const float*)d_in[14];
  const float* alin_w  = (const float*)d_in[15];
  const float* alin_b  = (const float*)d_in[16];
  const float* knorm_g = (const float*)d_in[17];
  const float* knorm_b = (const float*)d_in[18];
  const float* qnorm_g = (const float*)d_in[19];
  const float* qnorm_b = (const float*)d_in[20];
  const float* vnorm_g = (const float*)d_in[21];
  const float* vnorm_b = (const float*)d_in[22];
  const float* lin1_w  = (const float*)d_in[23];
  const float* lin1_b  = (const float*)d_in[24];
  const float* lin2_w  = (const float*)d_in[25];
  const float* lin2_b  = (const float*)d_in[26];

  // workspace layout
  float* feats  = (float*)d_ws;                         // 1,296,896 f
  float* F      = feats + (size_t)BATCH*NPIX*CH;        // 2,441,216 f
  float* statsE = F + (size_t)BATCH*NPIX*64;            // 128 f
  float* statsP = statsE + 128;                         // 384 f
  ushort* Qb    = (ushort*)(statsP + 384);              // 9,764,864 hw each
  ushort* Kb    = Qb + (size_t)BATCH*4*NPIX*64;
  ushort* Vb    = Kb + (size_t)BATCH*4*NPIX*64;
  ushort* Ew    = Vb + (size_t)BATCH*4*NPIX*64;         // 9,764,864 hw (bf16)
  ushort* w1T   = Ew + (size_t)BATCH*NPIX*256;          // 16,384 hw
  // alinT/WqkT overlay the F region (F written only after attention)
  ushort* alinT = (ushort*)F;                           // 640*608 hw
  ushort* WqkT  = alinT + 640*608;                      // 640*128 hw

  hipMemsetAsync(statsE, 0, 512*sizeof(float), stream);

  k_conv_feats<<<BATCH, 256, 0, stream>>>(x, conv1_w, conv1_b, conv2_w, conv2_b, feats);

  k_prep<<<640, 128, 0, stream>>>(alin_w, qlin_w, klin_w, lin1_w, alinT, WqkT, w1T);

  dim3 gp(4, BATCH, 3);
  k_proj_p1<<<gp, 256, 0, stream>>>(feats, kp_w, kp_b, qp_w, qp_b, vp_w, vp_b, statsP);
  k_proj_p2<<<gp, 256, 0, stream>>>(feats, kp_w, kp_b, qp_w, qp_b, vp_w, vp_b,
                                    knorm_g, knorm_b, qnorm_g, qnorm_b, vnorm_g, vnorm_b,
                                    statsP, Kb, Qb, Vb);

  static bool attr_set = false;
  if (!attr_set){
    hipFuncSetAttribute((const void*)k_attn, hipFuncAttributeMaxDynamicSharedMemorySize, 161792);
    attr_set = true;
  }
  dim3 ga(10, BATCH*4);
  k_attn<<<ga, 256, 161792, stream>>>(Qb, Kb, Vb, alinT, WqkT,
                                      qlin_b, klin_b, alin_b, Ew);

  dim3 gl(10, BATCH);
  k_lin1<<<gl, 256, 0, stream>>>(Ew, w1T, lin1_b, F, statsE);

  k_final<<<BATCH, 256, 0, stream>>>(F, statsE, lin2_w, lin2_b, (float*)d_out);
}

// Round 5
// 696.313 us; speedup vs baseline: 7.5433x; 1.2300x over previous
//
#include <hip/hip_runtime.h>
#include <hip/hip_bf16.h>
#include <math.h>

typedef __hip_bfloat16 bf16;
typedef unsigned short ushort;
typedef __attribute__((ext_vector_type(8))) short short8;
typedef __attribute__((ext_vector_type(4))) float float4v;

#define BATCH 64
#define NPIX 596
#define CH 34
#define PC 256

static __device__ __forceinline__ ushort f2bu(float v){ bf16 h = __float2bfloat16(v); return *(ushort*)&h; }
static __device__ __forceinline__ float eluf(float x){ return x > 0.f ? x : expm1f(x); }

// ---------------------------------------------------------------------------
// K1: conv1+relu -> conv2+relu -> feats (B, 596, 34) f32.
// ---------------------------------------------------------------------------
__global__ __launch_bounds__(256) void k_conv_feats(
    const float* __restrict__ x,
    const float* __restrict__ w1, const float* __restrict__ b1,
    const float* __restrict__ w2, const float* __restrict__ b2,
    float* __restrict__ feats)
{
  __shared__ float sw1[256];
  __shared__ float sb1[16];
  __shared__ float sw2[2048];
  __shared__ float sb2[32];
  __shared__ float h1[16*150*5];
  const int b = blockIdx.x, t = threadIdx.x;
  const float* xb = x + (size_t)b * 4*151*6;

  sw1[t]=w1[t];
  if (t<16) sb1[t]=b1[t];
  for (int i=t;i<2048;i+=256) sw2[i]=w2[i];
  if (t<32) sb2[t]=b2[t];
  __syncthreads();

  for (int i=t;i<12000;i+=256){
    int oc = i/750, rem = i-oc*750;
    int r = rem/5, cc = rem-(rem/5)*5;
    float acc = sb1[oc];
    #pragma unroll
    for (int ic=0;ic<4;ic++){
      const float* xp = xb + ic*906 + r*6 + cc;
      const float* wp = sw1 + oc*16 + ic*4;
      acc += xp[0]*wp[0] + xp[1]*wp[1] + xp[6]*wp[2] + xp[7]*wp[3];
    }
    h1[i] = fmaxf(acc, 0.f);
  }
  __syncthreads();

  float* fb = feats + (size_t)b*NPIX*CH;
  for (int i=t;i<32*NPIX;i+=256){
    int oc = i/NPIX, p = i - oc*NPIX;
    int r = p>>2, cc = p&3;
    float acc = sb2[oc];
    #pragma unroll
    for (int ic=0;ic<16;ic++){
      const float* hp = h1 + ic*750 + r*5 + cc;
      const float* wp = sw2 + oc*64 + ic*4;
      acc += hp[0]*wp[0] + hp[1]*wp[1] + hp[5]*wp[2] + hp[6]*wp[3];
    }
    fb[p*CH+oc] = fmaxf(acc, 0.f);
  }
  for (int p=t;p<NPIX;p+=256){
    fb[p*CH+32] = (float)(p&3)*0.25f;
    fb[p*CH+33] = (float)(p>>2)*(1.0f/149.0f);
  }
}

// ---------------------------------------------------------------------------
// K_prep: pack weights in MFMA B-fragment order, bf16.
// Fragment slot layout: 1KB per (tile, kchunk): lane l=(quad,ln) holds 8
// halves B[k = kchunk*32 + quad*8 + j][n = tile*16 + ln].
//   alinP: 40 tiles x 19 kchunks   (B = alin[c][n])
//   WqkP : 40 tiles x 4  kchunks   (B[k][n] = k<64 ? qlin[k][n] : klin[k-64][n])
//   w1T  : [n][e] plain transpose of lin1_w
// Total short8 slots: 48640 + 10240 + 2048 = 60928 -> grid 238 x 256.
// ---------------------------------------------------------------------------
__global__ __launch_bounds__(256) void k_prep(
    const float* __restrict__ aw, const float* __restrict__ qw, const float* __restrict__ kw,
    const float* __restrict__ l1w,
    ushort* __restrict__ alinP, ushort* __restrict__ WqkP, ushort* __restrict__ w1T)
{
  int s = blockIdx.x*256 + threadIdx.x;
  if (s < 48640){
    int tile = s/(19*64), rem = s%(19*64);
    int kk = rem>>6, l = rem&63;
    int n = tile*16 + (l&15);
    int c0 = kk*32 + (l>>4)*8;
    ushort out[8];
    #pragma unroll
    for (int i=0;i<8;i++){
      int c = c0+i;
      out[i] = (n<NPIX && c<NPIX) ? f2bu(aw[(size_t)c*NPIX + n]) : 0;
    }
    *(short8*)(alinP + (size_t)s*8) = *(short8*)out;
  } else if (s < 58880){
    int s2 = s - 48640;
    int tile = s2/(4*64), rem = s2%(4*64);
    int kk = rem>>6, l = rem&63;
    int n = tile*16 + (l&15);
    int k0 = kk*32 + (l>>4)*8;
    ushort out[8];
    #pragma unroll
    for (int i=0;i<8;i++){
      int k = k0+i;
      float v = 0.f;
      if (n<NPIX) v = (k<64) ? qw[(size_t)k*NPIX + n] : kw[(size_t)(k-64)*NPIX + n];
      out[i] = (n<NPIX) ? f2bu(v) : 0;
    }
    *(short8*)(WqkP + (size_t)s2*8) = *(short8*)out;
  } else {
    int s3 = s - 58880;           // 2048 slots
    int n = s3>>5, e0 = (s3&31)*8;
    ushort out[8];
    #pragma unroll
    for (int i=0;i<8;i++) out[i] = f2bu(l1w[(size_t)(e0+i)*64 + n]);
    *(short8*)(w1T + (size_t)s3*8) = *(short8*)out;
  }
}

// ---------------------------------------------------------------------------
// K_vt: pack V into fragment order. Per bh: VP slot g=(w*19+kk)*64+l holds
// V[j = kk*32 + quad*8 + jj][d = w*16 + ln].  4864 short8 per bh.
// ---------------------------------------------------------------------------
__global__ __launch_bounds__(256) void k_vt(
    const ushort* __restrict__ Vb, ushort* __restrict__ VP)
{
  extern __shared__ ushort vt[];     // 64 x 608
  const int bh = blockIdx.x, t = threadIdx.x;
  const ushort* Vp = Vb + (size_t)bh*NPIX*64;
  for (int g=t; g<4768; g+=256){     // 596*8
    int p = g>>3, d0 = (g&7)*8;
    short8 vv = *(const short8*)(Vp + (size_t)p*64 + d0);
    #pragma unroll
    for (int i=0;i<8;i++) vt[(d0+i)*608 + p] = ((ushort*)&vv)[i];
  }
  __syncthreads();
  for (int g=t; g<4864; g+=256){
    int w2 = g/1216, rem = g%1216;
    int kk = rem>>6, l = rem&63;
    int d = w2*16 + (l&15);
    int j0 = kk*32 + (l>>4)*8;
    ushort out[8];
    #pragma unroll
    for (int i=0;i<8;i++){
      int j = j0+i;
      out[i] = (j<NPIX) ? vt[d*608 + j] : 0;
    }
    *(short8*)(VP + ((size_t)bh*4864 + g)*8) = *(short8*)out;
  }
}

// ---------------------------------------------------------------------------
// P1: proj stats. grid (4 ptiles, 64 b, 3 which). atomic partial sums.
// ---------------------------------------------------------------------------
__global__ __launch_bounds__(256) void k_proj_p1(
    const float* __restrict__ feats,
    const float* __restrict__ kpw, const float* __restrict__ kpb,
    const float* __restrict__ qpw, const float* __restrict__ qpb,
    const float* __restrict__ vpw, const float* __restrict__ vpb,
    float* __restrict__ statsP)
{
  __shared__ float sw[CH*PC];
  __shared__ float sb[PC];
  __shared__ float sf[149*CH];
  __shared__ float red[8];
  const int pt = blockIdx.x, b = blockIdx.y, which = blockIdx.z, t = threadIdx.x;
  const float* W  = which==0 ? kpw : which==1 ? qpw : vpw;
  const float* Bv = which==0 ? kpb : which==1 ? qpb : vpb;
  for (int i=t;i<CH*PC;i+=256) sw[i]=W[i];
  sb[t]=Bv[t];
  const float* fb = feats + ((size_t)b*NPIX + pt*149)*CH;
  for (int i=t;i<149*CH;i+=256) sf[i]=fb[i];
  __syncthreads();
  float s=0.f, s2=0.f;
  for (int p=0;p<149;p++){
    float acc = sb[t];
    const float* fr = sf + p*CH;
    #pragma unroll
    for (int e=0;e<CH;e++) acc += fr[e]*sw[e*PC+t];
    s += acc; s2 += acc*acc;
  }
  #pragma unroll
  for (int o=32;o>0;o>>=1){ s += __shfl_down(s,o); s2 += __shfl_down(s2,o); }
  if ((t&63)==0){ red[t>>6]=s; red[4+(t>>6)]=s2; }
  __syncthreads();
  if (t==0){
    atomicAdd(&statsP[(which*64+b)*2],   red[0]+red[1]+red[2]+red[3]);
    atomicAdd(&statsP[(which*64+b)*2+1], red[4]+red[5]+red[6]+red[7]);
  }
}

// ---------------------------------------------------------------------------
// P2: proj recompute + LN + affine -> bf16 (B,4,596,64).
// ---------------------------------------------------------------------------
__global__ __launch_bounds__(256) void k_proj_p2(
    const float* __restrict__ feats,
    const float* __restrict__ kpw, const float* __restrict__ kpb,
    const float* __restrict__ qpw, const float* __restrict__ qpb,
    const float* __restrict__ vpw, const float* __restrict__ vpb,
    const float* __restrict__ kg, const float* __restrict__ kb_,
    const float* __restrict__ qg, const float* __restrict__ qb_,
    const float* __restrict__ vg, const float* __restrict__ vb_,
    const float* __restrict__ statsP,
    ushort* __restrict__ Kb, ushort* __restrict__ Qb, ushort* __restrict__ Vb)
{
  __shared__ float sw[CH*PC];
  __shared__ float sb[PC];
  __shared__ float sf[149*CH];
  const int pt = blockIdx.x, b = blockIdx.y, which = blockIdx.z, t = threadIdx.x;
  const float* W  = which==0 ? kpw : which==1 ? qpw : vpw;
  const float* Bv = which==0 ? kpb : which==1 ? qpb : vpb;
  const float* G  = which==0 ? kg  : which==1 ? qg  : vg;
  const float* Be = which==0 ? kb_ : which==1 ? qb_ : vb_;
  ushort* out     = which==0 ? Kb  : which==1 ? Qb  : Vb;
  for (int i=t;i<CH*PC;i+=256) sw[i]=W[i];
  sb[t]=Bv[t];
  const float* fb = feats + ((size_t)b*NPIX + pt*149)*CH;
  for (int i=t;i<149*CH;i+=256) sf[i]=fb[i];
  __syncthreads();
  const float n = (float)(NPIX*PC);
  const float S  = statsP[(which*64+b)*2];
  const float S2 = statsP[(which*64+b)*2+1];
  const float mu = S/n;
  const float rs = rsqrtf(S2/n - mu*mu + 1e-5f);
  const int h = t>>6, d = t&63;
  for (int p=0;p<149;p++){
    float acc = sb[t];
    const float* fr = sf + p*CH;
    #pragma unroll
    for (int e=0;e<CH;e++) acc += fr[e]*sw[e*PC+t];
    int pg = pt*149 + p;
    int gi = (h*NPIX+pg)*64 + d;
    float y = (acc-mu)*rs*G[gi] + Be[gi];
    out[((size_t)(b*4+h)*NPIX + pg)*64 + d] = f2bu(y);
  }
}

// ---------------------------------------------------------------------------
// K3: fused MFMA attention, M=64 rows/block, N=640 (40 tiles), no LDS
// staging: B-fragments stream from global (packed alinP/WqkP/VP), A-frags
// from a 78KB LDS strip.  LDS total 79,872 B -> 2 blocks/CU.
// grid (10 row-strips, 256 bh), 256 threads.
// ---------------------------------------------------------------------------
__global__ __launch_bounds__(256, 2) void k_attn(
    const ushort* __restrict__ Qb, const ushort* __restrict__ Kb,
    const ushort* __restrict__ alinP, const ushort* __restrict__ WqkP,
    const ushort* __restrict__ VP,
    const float* __restrict__ qbias, const float* __restrict__ kbias,
    const float* __restrict__ abias,
    ushort* __restrict__ Ew)
{
  extern __shared__ __align__(16) ushort sm[];
  ushort* strip = sm;                      // 64*616 = 39424 halves
  float*  red   = (float*)(sm + 39424);    // 256 f32

  const int t = threadIdx.x;
  const int w = t>>6, l = t&63, quad = l>>4, ln = l&15;
  const int rb = blockIdx.x, bh = blockIdx.y;
  const int b = bh>>2, h = bh&3;
  const int row0 = rb*64;
  const ushort* Qp = Qb + (size_t)bh*NPIX*64;
  const ushort* Kp = Kb + (size_t)bh*NPIX*64;

  float4v acc[4][10];
  #pragma unroll
  for (int ms=0;ms<4;ms++)
    #pragma unroll
    for (int i=0;i<10;i++) acc[ms][i] = (float4v){0.f,0.f,0.f,0.f};

  // ---------------- A0 = elu([Q|K] @ Wqk + qb + kb) ----------------
  #pragma unroll
  for (int kk=0;kk<4;kk++){
    short8 aq[4];
    #pragma unroll
    for (int ms=0;ms<4;ms++){
      int r = row0 + ms*16 + ln;
      short8 z = {0,0,0,0,0,0,0,0};
      aq[ms] = (r < NPIX)
        ? *(const short8*)((kk<2 ? Qp : Kp) + (size_t)r*64 + (kk&1)*32 + quad*8) : z;
    }
    #pragma unroll
    for (int i=0;i<10;i++){
      int tile = w + 4*i;
      short8 bf = *(const short8*)(WqkP + ((size_t)(tile*4 + kk)*64 + l)*8);
      #pragma unroll
      for (int ms=0;ms<4;ms++)
        acc[ms][i] = __builtin_amdgcn_mfma_f32_16x16x32_bf16(aq[ms], bf, acc[ms][i], 0,0,0);
    }
  }
  // epilogue: bias + elu -> strip
  #pragma unroll
  for (int i=0;i<10;i++){
    int t0 = w + 4*i;
    if (t0 < 38){
      int col = t0*16 + ln;
      bool cv = col < NPIX;
      float qkb = cv ? (qbias[col] + kbias[col]) : 0.f;
      #pragma unroll
      for (int ms=0;ms<4;ms++)
        #pragma unroll
        for (int r=0;r<4;r++){
          float v = 0.f;
          if (cv){ float xx = acc[ms][i][r] + qkb; v = xx > 0.f ? xx : __expf(xx) - 1.f; }
          strip[(ms*16+quad*4+r)*616 + col] = f2bu(v);
        }
    }
  }
  __syncthreads();

  // ---------------- S = A0 @ alin ----------------
  #pragma unroll
  for (int ms=0;ms<4;ms++)
    #pragma unroll
    for (int i=0;i<10;i++) acc[ms][i] = (float4v){0.f,0.f,0.f,0.f};
  for (int kk=0;kk<19;kk++){
    short8 af[4];
    #pragma unroll
    for (int ms=0;ms<4;ms++)
      af[ms] = *(const short8*)(strip + (ms*16+ln)*616 + kk*32 + quad*8);
    #pragma unroll
    for (int i=0;i<10;i++){
      int tile = w + 4*i;
      short8 bf = *(const short8*)(alinP + ((size_t)(tile*19 + kk)*64 + l)*8);
      #pragma unroll
      for (int ms=0;ms<4;ms++)
        acc[ms][i] = __builtin_amdgcn_mfma_f32_16x16x32_bf16(af[ms], bf, acc[ms][i], 0,0,0);
    }
  }
  __syncthreads();   // all strip reads done before P overwrites it

  // ---------------- softmax (exact, cross-wave) ----------------
  float M_[4][4], sum[4][4], inv[4][4];
  #pragma unroll
  for (int ms=0;ms<4;ms++)
    #pragma unroll
    for (int r=0;r<4;r++) M_[ms][r] = -1e30f;
  #pragma unroll
  for (int i=0;i<10;i++){
    int col = (w+4*i)*16 + ln;
    float ab = (col < NPIX) ? abias[col] : 0.f;
    #pragma unroll
    for (int ms=0;ms<4;ms++)
      #pragma unroll
      for (int r=0;r<4;r++){
        float s = (col < NPIX) ? acc[ms][i][r] + ab : -1e30f;
        acc[ms][i][r] = s;
        M_[ms][r] = fmaxf(M_[ms][r], s);
      }
  }
  #pragma unroll
  for (int ms=0;ms<4;ms++)
    #pragma unroll
    for (int r=0;r<4;r++)
      #pragma unroll
      for (int o=8;o>0;o>>=1) M_[ms][r] = fmaxf(M_[ms][r], __shfl_xor(M_[ms][r], o, 16));
  if (ln==0){
    #pragma unroll
    for (int ms=0;ms<4;ms++)
      #pragma unroll
      for (int r=0;r<4;r++) red[(ms*16+quad*4+r)*4 + w] = M_[ms][r];
  }
  __syncthreads();
  #pragma unroll
  for (int ms=0;ms<4;ms++)
    #pragma unroll
    for (int r=0;r<4;r++){
      float4v v = *(float4v*)&red[(ms*16+quad*4+r)*4];
      M_[ms][r] = fmaxf(fmaxf(v[0],v[1]), fmaxf(v[2],v[3]));
      sum[ms][r] = 0.f;
    }
  #pragma unroll
  for (int i=0;i<10;i++)
    #pragma unroll
    for (int ms=0;ms<4;ms++)
      #pragma unroll
      for (int r=0;r<4;r++){
        float e = __expf(acc[ms][i][r] - M_[ms][r]);
        acc[ms][i][r] = e;
        sum[ms][r] += e;
      }
  #pragma unroll
  for (int ms=0;ms<4;ms++)
    #pragma unroll
    for (int r=0;r<4;r++)
      #pragma unroll
      for (int o=8;o>0;o>>=1) sum[ms][r] += __shfl_xor(sum[ms][r], o, 16);
  __syncthreads();
  if (ln==0){
    #pragma unroll
    for (int ms=0;ms<4;ms++)
      #pragma unroll
      for (int r=0;r<4;r++) red[(ms*16+quad*4+r)*4 + w] = sum[ms][r];
  }
  __syncthreads();
  #pragma unroll
  for (int ms=0;ms<4;ms++)
    #pragma unroll
    for (int r=0;r<4;r++){
      float4v v = *(float4v*)&red[(ms*16+quad*4+r)*4];
      inv[ms][r] = 1.f / (v[0]+v[1]+v[2]+v[3]);
    }
  #pragma unroll
  for (int i=0;i<10;i++){
    int t0 = w + 4*i;
    if (t0 < 38){
      int col = t0*16 + ln;
      #pragma unroll
      for (int ms=0;ms<4;ms++)
        #pragma unroll
        for (int r=0;r<4;r++)
          strip[(ms*16+quad*4+r)*616 + col] = f2bu(acc[ms][i][r] * inv[ms][r]);
    }
  }
  __syncthreads();

  // ---------------- E = P @ V ----------------
  float4v ve[4];
  #pragma unroll
  for (int ms=0;ms<4;ms++) ve[ms] = (float4v){0.f,0.f,0.f,0.f};
  for (int kk=0;kk<19;kk++){
    short8 bf = *(const short8*)(VP + ((size_t)bh*4864 + (w*19 + kk)*64 + l)*8);
    #pragma unroll
    for (int ms=0;ms<4;ms++){
      short8 af = *(const short8*)(strip + (ms*16+ln)*616 + kk*32 + quad*8);
      ve[ms] = __builtin_amdgcn_mfma_f32_16x16x32_bf16(af, bf, ve[ms], 0,0,0);
    }
  }
  #pragma unroll
  for (int ms=0;ms<4;ms++)
    #pragma unroll
    for (int r=0;r<4;r++){
      int p = row0 + ms*16 + quad*4 + r;
      if (p < NPIX)
        Ew[((size_t)b*NPIX + p)*256 + h*64 + w*16 + ln] = f2bu(ve[ms][r]);
    }
}

// ---------------------------------------------------------------------------
// K4: lin1 via MFMA + relu + per-batch LN stats. grid (10 rowblocks, 64 b).
// ---------------------------------------------------------------------------
__global__ __launch_bounds__(256) void k_lin1(
    const ushort* __restrict__ Ew, const ushort* __restrict__ w1T,
    const float* __restrict__ bias,
    float* __restrict__ F, float* __restrict__ stats)
{
  __shared__ ushort sw1[64*264];
  __shared__ float red[8];
  const int t = threadIdx.x;
  const int w = t>>6, l = t&63, quad = l>>4, ln = l&15;
  const int rb = blockIdx.x, b = blockIdx.y;
  for (int g=t; g<2048; g+=256){
    int row = g>>5, q = g&31;
    *(short8*)(sw1 + row*264 + q*8) = *(const short8*)(w1T + row*256 + q*8);
  }
  __syncthreads();
  float4v acc[4];
  #pragma unroll
  for (int ms=0;ms<4;ms++) acc[ms] = (float4v){0.f,0.f,0.f,0.f};
  #pragma unroll
  for (int kk=0;kk<8;kk++){
    short8 bf = *(const short8*)(sw1 + (w*16+ln)*264 + kk*32 + quad*8);
    #pragma unroll
    for (int ms=0;ms<4;ms++){
      int p = rb*64 + ms*16 + ln;
      size_t rowi = (size_t)b*NPIX + (p < NPIX ? p : 0);
      short8 a = *(const short8*)(Ew + rowi*256 + kk*32 + quad*8);
      acc[ms] = __builtin_amdgcn_mfma_f32_16x16x32_bf16(a, bf, acc[ms], 0,0,0);
    }
  }
  const int col = w*16 + ln;
  const float bc = bias[col];
  float s=0.f, s2=0.f;
  #pragma unroll
  for (int ms=0;ms<4;ms++)
    #pragma unroll
    for (int r=0;r<4;r++){
      int p = rb*64 + ms*16 + quad*4 + r;
      if (p < NPIX){
        float v = fmaxf(acc[ms][r] + bc, 0.f);
        F[((size_t)b*NPIX + p)*64 + col] = v;
        s += v; s2 += v*v;
      }
    }
  #pragma unroll
  for (int o=32;o>0;o>>=1){ s += __shfl_down(s,o); s2 += __shfl_down(s2,o); }
  if (l==0){ red[w]=s; red[4+w]=s2; }
  __syncthreads();
  if (t==0){
    atomicAdd(&stats[b*2],   red[0]+red[1]+red[2]+red[3]);
    atomicAdd(&stats[b*2+1], red[4]+red[5]+red[6]+red[7]);
  }
}

// ---------------------------------------------------------------------------
// K5: LN (no affine) + max over pixels (commutes: rs>0) + lin2 + elu.
// ---------------------------------------------------------------------------
__global__ __launch_bounds__(256) void k_final(
    const float* __restrict__ F, const float* __restrict__ stats,
    const float* __restrict__ w2, const float* __restrict__ b2v,
    float* __restrict__ out)
{
  __shared__ float cm[256];
  __shared__ float nm[64];
  const int b = blockIdx.x, t = threadIdx.x;
  const int d = t&63, grp = t>>6;
  const float* Fb = F + (size_t)b*NPIX*64;
  float m = -1e30f;
  for (int p=grp;p<NPIX;p+=4) m = fmaxf(m, Fb[p*64+d]);
  cm[t]=m;
  __syncthreads();
  if (t<64){
    float mm = fmaxf(fmaxf(cm[t],cm[t+64]), fmaxf(cm[t+128],cm[t+192]));
    const float n = (float)(NPIX*64);
    float S = stats[b*2], S2 = stats[b*2+1];
    float mu = S/n, var = S2/n - mu*mu;
    nm[t] = (mm - mu) * rsqrtf(var + 1e-5f);
  }
  __syncthreads();
  if (t<10){
    float acc = b2v[t];
    for (int e=0;e<64;e++) acc += nm[e]*w2[e*10+t];
    out[b*10+t] = eluf(acc);
  }
}

// ---------------------------------------------------------------------------
extern "C" void kernel_launch(void* const* d_in, const int* in_sizes, int n_in,
                              void* d_out, int out_size, void* d_ws, size_t ws_size,
                              hipStream_t stream)
{
  const float* x       = (const float*)d_in[0];
  const float* conv1_w = (const float*)d_in[1];
  const float* conv1_b = (const float*)d_in[2];
  const float* conv2_w = (const float*)d_in[3];
  const float* conv2_b = (const float*)d_in[4];
  const float* kp_w    = (const float*)d_in[5];
  const float* kp_b    = (const float*)d_in[6];
  const float* qp_w    = (const float*)d_in[7];
  const float* qp_b    = (const float*)d_in[8];
  const float* vp_w    = (const float*)d_in[9];
  const float* vp_b    = (const float*)d_in[10];
  const float* klin_w  = (const float*)d_in[11];
  const float* klin_b  = (const float*)d_in[12];
  const float* qlin_w  = (const float*)d_in[13];
  const float* qlin_b  = (const float*)d_in[14];
  const float* alin_w  = (const float*)d_in[15];
  const float* alin_b  = (const float*)d_in[16];
  const float* knorm_g = (const float*)d_in[17];
  const float* knorm_b = (const float*)d_in[18];
  const float* qnorm_g = (const float*)d_in[19];
  const float* qnorm_b = (const float*)d_in[20];
  const float* vnorm_g = (const float*)d_in[21];
  const float* vnorm_b = (const float*)d_in[22];
  const float* lin1_w  = (const float*)d_in[23];
  const float* lin1_b  = (const float*)d_in[24];
  const float* lin2_w  = (const float*)d_in[25];
  const float* lin2_b  = (const float*)d_in[26];

  // workspace layout
  float* feats  = (float*)d_ws;                         // 1,296,896 f
  float* F      = feats + (size_t)BATCH*NPIX*CH;        // 2,441,216 f
  float* statsE = F + (size_t)BATCH*NPIX*64;            // 128 f
  float* statsP = statsE + 128;                         // 384 f
  ushort* Qb    = (ushort*)(statsP + 384);              // 9,764,864 hw each
  ushort* Kb    = Qb + (size_t)BATCH*4*NPIX*64;
  ushort* Vb    = Kb + (size_t)BATCH*4*NPIX*64;
  ushort* Ew    = Vb + (size_t)BATCH*4*NPIX*64;         // 9,764,864 hw
  ushort* w1T   = Ew + (size_t)BATCH*NPIX*256;          // 16,384 hw
  ushort* alinP = w1T + 16384;                          // 389,120 hw
  ushort* WqkP  = alinP + 389120;                       // 81,920 hw
  ushort* VP    = WqkP + 81920;                         // 9,961,472 hw

  hipMemsetAsync(statsE, 0, 512*sizeof(float), stream);

  k_conv_feats<<<BATCH, 256, 0, stream>>>(x, conv1_w, conv1_b, conv2_w, conv2_b, feats);

  k_prep<<<238, 256, 0, stream>>>(alin_w, qlin_w, klin_w, lin1_w, alinP, WqkP, w1T);

  dim3 gp(4, BATCH, 3);
  k_proj_p1<<<gp, 256, 0, stream>>>(feats, kp_w, kp_b, qp_w, qp_b, vp_w, vp_b, statsP);
  k_proj_p2<<<gp, 256, 0, stream>>>(feats, kp_w, kp_b, qp_w, qp_b, vp_w, vp_b,
                                    knorm_g, knorm_b, qnorm_g, qnorm_b, vnorm_g, vnorm_b,
                                    statsP, Kb, Qb, Vb);

  static bool attr_set = false;
  if (!attr_set){
    hipFuncSetAttribute((const void*)k_vt,   hipFuncAttributeMaxDynamicSharedMemorySize, 77824);
    hipFuncSetAttribute((const void*)k_attn, hipFuncAttributeMaxDynamicSharedMemorySize, 79872);
    attr_set = true;
  }
  k_vt<<<BATCH*4, 256, 77824, stream>>>(Vb, VP);

  dim3 ga(10, BATCH*4);
  k_attn<<<ga, 256, 79872, stream>>>(Qb, Kb, alinP, WqkP, VP,
                                     qlin_b, klin_b, alin_b, Ew);

  dim3 gl(10, BATCH);
  k_lin1<<<gl, 256, 0, stream>>>(Ew, w1T, lin1_b, F, statsE);

  k_final<<<BATCH, 256, 0, stream>>>(F, statsE, lin2_w, lin2_b, (float*)d_out);
}